// Round 6
// baseline (115.698 us; speedup 1.0000x reference)
//
#include <hip/hip_runtime.h>

#define B_  16
#define C_  256
#define O_  256

typedef short    bf16x8 __attribute__((ext_vector_type(8)));
typedef float    f32x16 __attribute__((ext_vector_type(16)));
typedef unsigned u32x4  __attribute__((ext_vector_type(4)));
typedef unsigned u32x2  __attribute__((ext_vector_type(2)));

// xT layout: [b][cc][yphys 0..65][lh 0..1][col 0..65][8c] bf16
#define XROW_SH  1056
#define XBC_SH   (66 * XROW_SH)
#define XT_BYTES ((size_t)B_ * 16 * XBC_SH * 2)

#define WTILE_SH 9216
#define WORP_BYTES ((size_t)B_ * 16 * 4 * WTILE_SH * 2)

#define XBUF_SH  10752

__device__ __forceinline__ unsigned cvtpk(float lo, float hi) {
    unsigned r;
    asm("v_cvt_pk_bf16_f32 %0, %1, %2" : "=v"(r) : "v"(lo), "v"(hi));
    return r;
}

__device__ __forceinline__ void gload16(const void* g, void* l) {
    __builtin_amdgcn_global_load_lds(
        (const __attribute__((address_space(1))) unsigned int*)g,
        (__attribute__((address_space(3))) unsigned int*)l, 16, 0, 0);
}

// ---------------------------------------------------------------- xprep -----
// Thread = 1 pixel x 8 channels: 8 coalesced row loads -> cvt_pk -> one 16B
// store in conv layout. No LDS transpose. Pool partials fused.
// grid (cg=32, b=16, z=4); block 256 = 4 waves x 64 px.
__global__ __launch_bounds__(256) void xprep_kernel(const float* __restrict__ x,
                                                    short* __restrict__ xT,
                                                    float* __restrict__ pooled4) {
    const int cg = blockIdx.x;          // 8-channel group: cc = cg>>1, lh = cg&1
    const int b  = blockIdx.y;
    const int z  = blockIdx.z;          // 16-row band
    const int t  = threadIdx.x;
    const int lane = t & 63, wv = t >> 6;
    const int cc = cg >> 1, lh = cg & 1;

    short* xTb = xT + (size_t)(b * 16 + cc) * XBC_SH;
    const float* xb = x + ((size_t)(b * C_ + cg * 8) << 12);

    {   // halo zeros for this (cc,lh) slice
        u32x4 zv = {0, 0, 0, 0};
        if (t < 32) {                   // side cols of this band's 16 rows
            int r   = z * 16 + 1 + (t >> 1);
            int col = (t & 1) ? 65 : 0;
            *(u32x4*)&xTb[r * XROW_SH + lh * 528 + col * 8] = zv;
        }
        if (z == 0 || z == 3) {         // full top/bottom halo row
            int row = (z == 0) ? 0 : 65;
            if (t < 66) *(u32x4*)&xTb[row * XROW_SH + lh * 528 + t * 8] = zv;
        }
    }

    float s[8] = {0.f, 0.f, 0.f, 0.f, 0.f, 0.f, 0.f, 0.f};
    const int px = lane;
#pragma unroll
    for (int r = 0; r < 4; ++r) {
        const int row = z * 16 + wv * 4 + r;
        const float* src = xb + row * 64 + px;
        float v[8];
#pragma unroll
        for (int i = 0; i < 8; ++i) { v[i] = src[(size_t)i << 12]; s[i] += v[i]; }
        u32x4 d = { cvtpk(v[0], v[1]), cvtpk(v[2], v[3]),
                    cvtpk(v[4], v[5]), cvtpk(v[6], v[7]) };
        *(u32x4*)&xTb[(row + 1) * XROW_SH + lh * 528 + (px + 1) * 8] = d;
    }

#pragma unroll
    for (int i = 0; i < 8; ++i)
#pragma unroll
        for (int off = 32; off; off >>= 1) s[i] += __shfl_xor(s[i], off, 64);

    __shared__ float pr[4][8];
    if (lane == 0) {
#pragma unroll
        for (int i = 0; i < 8; ++i) pr[wv][i] = s[i];
    }
    __syncthreads();
    if (t < 8) {
        float v = pr[0][t] + pr[1][t] + pr[2][t] + pr[3][t];
        pooled4[(z * B_ + b) * C_ + cg * 8 + t] = v * (1.0f / 4096.0f);
    }
}

// ---------------------------------------------------------------- mix -------
__global__ __launch_bounds__(256) void mix_kernel(const float* __restrict__ bank,
                                                  const float* __restrict__ pooled4,
                                                  const float* __restrict__ W_fc,
                                                  const float* __restrict__ b_fc,
                                                  short* __restrict__ worp) {
    const int b  = blockIdx.x;
    const int cc = blockIdx.y;
    const int t  = threadIdx.x, lane = t & 63, wid = t >> 6;

    __shared__ float bankL[4 * 64 * 37];
    __shared__ float lg[4];

    {
        float s = 0.f;
#pragma unroll
        for (int q = 0; q < 4; ++q) {
            int c = lane * 4 + q;
            float pv = pooled4[b * C_ + c] + pooled4[(B_ + b) * C_ + c]
                     + pooled4[(2 * B_ + b) * C_ + c] + pooled4[(3 * B_ + b) * C_ + c];
            s += pv * W_fc[wid * C_ + c];
        }
#pragma unroll
        for (int off = 32; off; off >>= 1) s += __shfl_down(s, off, 64);
        if (lane == 0) lg[wid] = s + b_fc[wid];
    }
    __syncthreads();
    float l0 = lg[0], l1 = lg[1], l2 = lg[2], l3 = lg[3];
    float mx = fmaxf(fmaxf(l0, l1), fmaxf(l2, l3));
    float e0 = expf(l0 - mx), e1 = expf(l1 - mx), e2 = expf(l2 - mx), e3 = expf(l3 - mx);
    float inv = 1.f / (e0 + e1 + e2 + e3);
    const float cf0 = e0 * inv, cf1 = e1 * inv, cf2 = e2 * inv, cf3 = e3 * inv;

    const int oq  = t >> 6;
    const int o64 = t & 63;

    for (int sub = 0; sub < 4; ++sub) {
        __syncthreads();
        for (int i = t; i < 9216; i += 256) {
            int run = i / 36, e = i % 36;
            bankL[run * 37 + e] = bank[((size_t)run * C_ + cc * 16 + sub * 4) * 9 + e];
        }
        __syncthreads();

        const int lhs = sub >> 1;
        const float* bp = &bankL[o64 * 37];
#pragma unroll
        for (int ti = 0; ti < 3; ++ti)
#pragma unroll
            for (int tj = 0; tj < 3; ++tj) {
                int si, sj;
                if      (oq == 0) { si = ti;     sj = tj;     }
                else if (oq == 1) { si = tj;     sj = 2 - ti; }
                else if (oq == 2) { si = 2 - ti; sj = 2 - tj; }
                else              { si = 2 - tj; sj = ti;     }
                const int sij = si * 3 + sj;
                float v[4];
#pragma unroll
                for (int c4 = 0; c4 < 4; ++c4) {
                    const float* q = bp + c4 * 9 + sij;
                    v[c4] = cf0 * q[0] + cf1 * q[64 * 37] + cf2 * q[2 * 64 * 37]
                          + cf3 * q[3 * 64 * 37];
                }
                u32x2 d = { cvtpk(v[0], v[1]), cvtpk(v[2], v[3]) };
                size_t base = (((((size_t)(b * 16 + cc) * 4 + oq) * 9 + (ti * 3 + tj)) * 2
                                + lhs) * 64 + o64) * 8 + (sub & 1) * 4;
                *(u32x2*)&worp[base] = d;
            }
    }
}

// ---------------------------------------------------------------- conv ------
// 64 o x 512 px per block, 4 waves. x staged via gload_lds (double-buffered,
// LDS 43 KB); w A-fragments loaded DIRECTLY global->VGPR (identical across
// waves, L2-resident, coalesced 16B/lane) — no w LDS traffic at all.
__global__ __launch_bounds__(256, 2)
void conv_mfma(const short* __restrict__ xT, const short* __restrict__ worp,
               float* __restrict__ out) {
    __shared__ short lds[2 * XBUF_SH];          // 43,008 B

    const int g    = blockIdx.x;
    const int w    = (g & 7) * 64 + (g >> 3);   // XCD swizzle (bijective)
    const int oq   = w & 3;
    const int m    = w >> 2;
    const int rowt = m & 7;
    const int b    = m >> 3;
    const int y0   = rowt * 8;

    const int t    = threadIdx.x;
    const int lane = t & 63;
    const int wid  = t >> 6;
    const int l31  = lane & 31;
    const int lh   = lane >> 5;

    const char* xsrcB = (const char*)xT
        + ((size_t)(b * 16) * XBC_SH + (size_t)y0 * XROW_SH) * 2 + lane * 16;
    // per-(b,oq) w tile; per-lane A offset inside a tap: ((lh)*64 + oh*32 + l31)*8
    const short* wq = worp + (((size_t)(b * 16) * 4) + oq) * WTILE_SH;

#define STAGE(ccc, p)                                                           \
    { const char* xs = xsrcB + (size_t)(ccc) * (XBC_SH * 2);                    \
      char* xd = (char*)lds + (p) * (XBUF_SH * 2);                              \
      for (int u = wid; u < 21; u += 4) gload16(xs + u * 1024, xd + u * 1024); }

#define BRD(r, s) (*(const bf16x8*)&xcur[(((r) * 2 + lh) * 66 + (s) + l31) * 8])

    f32x16 acc0[4] = {}, acc1[4] = {};

    STAGE(0, 0);
    __syncthreads();

    for (int cc = 0; cc < 16; ++cc) {
        const int p = cc & 1;
        const short* wsc = wq + (size_t)cc * (4 * WTILE_SH);

        // A-frags for this chunk: 18 x dwordx4, issued before x prefetch so
        // their waits don't drain the newer x gloads.
        bf16x8 Af[3][3][2];
#pragma unroll
        for (int i = 0; i < 3; ++i)
#pragma unroll
            for (int j = 0; j < 3; ++j)
#pragma unroll
                for (int oh = 0; oh < 2; ++oh)
                    Af[i][j][oh] = *(const bf16x8*)
                        (wsc + (((i * 3 + j) * 2 + lh) * 64 + oh * 32 + l31) * 8);

        if (cc < 15) STAGE(cc + 1, p ^ 1);

        const short* xcur = lds + p * XBUF_SH;
        __builtin_amdgcn_s_setprio(1);
#pragma unroll
        for (int i = 0; i < 3; ++i)
#pragma unroll
            for (int j = 0; j < 3; ++j) {
                bf16x8 B00 = BRD(2 * wid + i,     j);
                bf16x8 B01 = BRD(2 * wid + i,     32 + j);
                bf16x8 B10 = BRD(2 * wid + i + 1, j);
                bf16x8 B11 = BRD(2 * wid + i + 1, 32 + j);
                acc0[0] = __builtin_amdgcn_mfma_f32_32x32x16_bf16(Af[i][j][0], B00, acc0[0], 0, 0, 0);
                acc1[0] = __builtin_amdgcn_mfma_f32_32x32x16_bf16(Af[i][j][1], B00, acc1[0], 0, 0, 0);
                acc0[1] = __builtin_amdgcn_mfma_f32_32x32x16_bf16(Af[i][j][0], B01, acc0[1], 0, 0, 0);
                acc1[1] = __builtin_amdgcn_mfma_f32_32x32x16_bf16(Af[i][j][1], B01, acc1[1], 0, 0, 0);
                acc0[2] = __builtin_amdgcn_mfma_f32_32x32x16_bf16(Af[i][j][0], B10, acc0[2], 0, 0, 0);
                acc1[2] = __builtin_amdgcn_mfma_f32_32x32x16_bf16(Af[i][j][1], B10, acc1[2], 0, 0, 0);
                acc0[3] = __builtin_amdgcn_mfma_f32_32x32x16_bf16(Af[i][j][0], B11, acc0[3], 0, 0, 0);
                acc1[3] = __builtin_amdgcn_mfma_f32_32x32x16_bf16(Af[i][j][1], B11, acc1[3], 0, 0, 0);
            }
        __builtin_amdgcn_s_setprio(0);
        __syncthreads();
    }
#undef STAGE
#undef BRD

#pragma unroll
    for (int pf = 0; pf < 4; ++pf) {
        const int yb  = y0 + 2 * wid + (pf >> 1);
        const int xcb = 32 * (pf & 1) + l31;
#pragma unroll
        for (int r = 0; r < 16; ++r) {
            const int orow = (r & 3) + 8 * (r >> 2) + 4 * lh;
            const int o0   = oq * 64 + orow;
            __builtin_nontemporal_store(acc0[pf][r],
                &out[((size_t)(b * O_ + o0)      << 12) + yb * 64 + xcb]);
            __builtin_nontemporal_store(acc1[pf][r],
                &out[((size_t)(b * O_ + o0 + 32) << 12) + yb * 64 + xcb]);
        }
    }
}

// ---------------------------------------------------------------- launch ----
extern "C" void kernel_launch(void* const* d_in, const int* in_sizes, int n_in,
                              void* d_out, int out_size, void* d_ws, size_t ws_size,
                              hipStream_t stream) {
    const float* x    = (const float*)d_in[0];
    const float* W_fc = (const float*)d_in[1];
    const float* b_fc = (const float*)d_in[2];
    const float* bank = (const float*)d_in[3];
    float* out = (float*)d_out;

    short* xTb     = (short*)d_ws;
    short* worp    = (short*)((char*)d_ws + XT_BYTES);
    float* pooled4 = (float*)((char*)d_ws + XT_BYTES + WORP_BYTES);

    xprep_kernel<<<dim3(32, 16, 4), 256, 0, stream>>>(x, xTb, pooled4);
    mix_kernel<<<dim3(B_, 16), 256, 0, stream>>>(bank, pooled4, W_fc, b_fc, worp);
    conv_mfma<<<512, 256, 0, stream>>>(xTb, worp, out);
}

// Round 7
// 111.547 us; speedup vs baseline: 1.0372x; 1.0372x over previous
//
#include <hip/hip_runtime.h>

#define B_  16
#define C_  256
#define O_  256

typedef short    bf16x8 __attribute__((ext_vector_type(8)));
typedef float    f32x16 __attribute__((ext_vector_type(16)));
typedef unsigned u32x4  __attribute__((ext_vector_type(4)));
typedef unsigned u32x2  __attribute__((ext_vector_type(2)));

// xT layout: [b][cc][yphys 0..65][lh 0..1][col 0..65][8c] bf16
#define XROW_SH  1056
#define XBC_SH   (66 * XROW_SH)
#define XT_BYTES ((size_t)B_ * 16 * XBC_SH * 2)

#define WTILE_SH 9216
#define WORP_BYTES ((size_t)B_ * 16 * 4 * WTILE_SH * 2)

#define XBUF_SH  10752

__device__ __forceinline__ unsigned cvtpk(float lo, float hi) {
    unsigned r;
    asm("v_cvt_pk_bf16_f32 %0, %1, %2" : "=v"(r) : "v"(lo), "v"(hi));
    return r;
}

__device__ __forceinline__ void gload16(const void* g, void* l) {
    __builtin_amdgcn_global_load_lds(
        (const __attribute__((address_space(1))) unsigned int*)g,
        (__attribute__((address_space(3))) unsigned int*)l, 16, 0, 0);
}

// ---------------------------------------------------------------- xprep -----
// Thread = 1 pixel x 8 channels: coalesced row loads -> cvt_pk -> one 16B
// store in conv layout. No LDS transpose. Pool partials fused.
__global__ __launch_bounds__(256) void xprep_kernel(const float* __restrict__ x,
                                                    short* __restrict__ xT,
                                                    float* __restrict__ pooled4) {
    const int cg = blockIdx.x;
    const int b  = blockIdx.y;
    const int z  = blockIdx.z;
    const int t  = threadIdx.x;
    const int lane = t & 63, wv = t >> 6;
    const int cc = cg >> 1, lh = cg & 1;

    short* xTb = xT + (size_t)(b * 16 + cc) * XBC_SH;
    const float* xb = x + ((size_t)(b * C_ + cg * 8) << 12);

    {   // halo zeros for this (cc,lh) slice
        u32x4 zv = {0, 0, 0, 0};
        if (t < 32) {
            int r   = z * 16 + 1 + (t >> 1);
            int col = (t & 1) ? 65 : 0;
            *(u32x4*)&xTb[r * XROW_SH + lh * 528 + col * 8] = zv;
        }
        if (z == 0 || z == 3) {
            int row = (z == 0) ? 0 : 65;
            if (t < 66) *(u32x4*)&xTb[row * XROW_SH + lh * 528 + t * 8] = zv;
        }
    }

    float s[8] = {0.f, 0.f, 0.f, 0.f, 0.f, 0.f, 0.f, 0.f};
    const int px = lane;
#pragma unroll
    for (int r = 0; r < 4; ++r) {
        const int row = z * 16 + wv * 4 + r;
        const float* src = xb + row * 64 + px;
        float v[8];
#pragma unroll
        for (int i = 0; i < 8; ++i) { v[i] = src[(size_t)i << 12]; s[i] += v[i]; }
        u32x4 d = { cvtpk(v[0], v[1]), cvtpk(v[2], v[3]),
                    cvtpk(v[4], v[5]), cvtpk(v[6], v[7]) };
        *(u32x4*)&xTb[(row + 1) * XROW_SH + lh * 528 + (px + 1) * 8] = d;
    }

#pragma unroll
    for (int i = 0; i < 8; ++i)
#pragma unroll
        for (int off = 32; off; off >>= 1) s[i] += __shfl_xor(s[i], off, 64);

    __shared__ float pr[4][8];
    if (lane == 0) {
#pragma unroll
        for (int i = 0; i < 8; ++i) pr[wv][i] = s[i];
    }
    __syncthreads();
    if (t < 8) {
        float v = pr[0][t] + pr[1][t] + pr[2][t] + pr[3][t];
        pooled4[(z * B_ + b) * C_ + cg * 8 + t] = v * (1.0f / 4096.0f);
    }
}

// ---------------------------------------------------------------- mix -------
__global__ __launch_bounds__(256) void mix_kernel(const float* __restrict__ bank,
                                                  const float* __restrict__ pooled4,
                                                  const float* __restrict__ W_fc,
                                                  const float* __restrict__ b_fc,
                                                  short* __restrict__ worp) {
    const int b  = blockIdx.x;
    const int cc = blockIdx.y;
    const int t  = threadIdx.x, lane = t & 63, wid = t >> 6;

    __shared__ float bankL[4 * 64 * 37];
    __shared__ float lg[4];

    {
        float s = 0.f;
#pragma unroll
        for (int q = 0; q < 4; ++q) {
            int c = lane * 4 + q;
            float pv = pooled4[b * C_ + c] + pooled4[(B_ + b) * C_ + c]
                     + pooled4[(2 * B_ + b) * C_ + c] + pooled4[(3 * B_ + b) * C_ + c];
            s += pv * W_fc[wid * C_ + c];
        }
#pragma unroll
        for (int off = 32; off; off >>= 1) s += __shfl_down(s, off, 64);
        if (lane == 0) lg[wid] = s + b_fc[wid];
    }
    __syncthreads();
    float l0 = lg[0], l1 = lg[1], l2 = lg[2], l3 = lg[3];
    float mx = fmaxf(fmaxf(l0, l1), fmaxf(l2, l3));
    float e0 = expf(l0 - mx), e1 = expf(l1 - mx), e2 = expf(l2 - mx), e3 = expf(l3 - mx);
    float inv = 1.f / (e0 + e1 + e2 + e3);
    const float cf0 = e0 * inv, cf1 = e1 * inv, cf2 = e2 * inv, cf3 = e3 * inv;

    const int oq  = t >> 6;
    const int o64 = t & 63;

    for (int sub = 0; sub < 4; ++sub) {
        __syncthreads();
        for (int i = t; i < 9216; i += 256) {
            int run = i / 36, e = i % 36;
            bankL[run * 37 + e] = bank[((size_t)run * C_ + cc * 16 + sub * 4) * 9 + e];
        }
        __syncthreads();

        const int lhs = sub >> 1;
        const float* bp = &bankL[o64 * 37];
#pragma unroll
        for (int ti = 0; ti < 3; ++ti)
#pragma unroll
            for (int tj = 0; tj < 3; ++tj) {
                int si, sj;
                if      (oq == 0) { si = ti;     sj = tj;     }
                else if (oq == 1) { si = tj;     sj = 2 - ti; }
                else if (oq == 2) { si = 2 - ti; sj = 2 - tj; }
                else              { si = 2 - tj; sj = ti;     }
                const int sij = si * 3 + sj;
                float v[4];
#pragma unroll
                for (int c4 = 0; c4 < 4; ++c4) {
                    const float* q = bp + c4 * 9 + sij;
                    v[c4] = cf0 * q[0] + cf1 * q[64 * 37] + cf2 * q[2 * 64 * 37]
                          + cf3 * q[3 * 64 * 37];
                }
                u32x2 d = { cvtpk(v[0], v[1]), cvtpk(v[2], v[3]) };
                size_t base = (((((size_t)(b * 16 + cc) * 4 + oq) * 9 + (ti * 3 + tj)) * 2
                                + lhs) * 64 + o64) * 8 + (sub & 1) * 4;
                *(u32x2*)&worp[base] = d;
            }
    }
}

// ---------------------------------------------------------------- conv ------
// 64 o x 512 px per block, 4 waves; gload_lds double-buffer (x and w both in
// LDS).  Each chunk split into 3 tap-row PHASES: {next-row ds_reads | STAGE}
// -> raw s_barrier -> setprio(1) MFMA cluster.  Phase barriers create the
// cross-wave role split so LDS and MFMA pipes run in counterphase instead of
// convoying (round-5 measured: pipes serialized, util 50%).
__global__ __launch_bounds__(256, 2)
void conv_mfma(const short* __restrict__ xT, const short* __restrict__ worp,
               float* __restrict__ out) {
    __shared__ short lds[2 * XBUF_SH + 2 * WTILE_SH];   // 79,872 B

    const int g    = blockIdx.x;
    const int w    = (g & 7) * 64 + (g >> 3);   // XCD swizzle (bijective)
    const int oq   = w & 3;
    const int m    = w >> 2;
    const int rowt = m & 7;
    const int b    = m >> 3;
    const int y0   = rowt * 8;

    const int t    = threadIdx.x;
    const int lane = t & 63;
    const int wid  = t >> 6;
    const int l31  = lane & 31;
    const int lh   = lane >> 5;

    const char* xsrcB = (const char*)xT
        + ((size_t)(b * 16) * XBC_SH + (size_t)y0 * XROW_SH) * 2 + lane * 16;
    const char* wsrcB = (const char*)worp
        + (((size_t)(b * 16) * 4) + oq) * (WTILE_SH * 2) + lane * 16;

#define STAGE(ccc, p)                                                           \
    { const char* xs = xsrcB + (size_t)(ccc) * (XBC_SH * 2);                    \
      const char* ws = wsrcB + (size_t)(ccc) * (4 * WTILE_SH * 2);              \
      char* xd = (char*)lds + (p) * (XBUF_SH * 2);                              \
      char* wd = (char*)lds + 2 * (XBUF_SH * 2) + (p) * (WTILE_SH * 2);         \
      for (int u = wid; u < 21; u += 4) gload16(xs + u * 1024, xd + u * 1024);  \
      for (int u = wid; u < 18; u += 4) gload16(ws + u * 1024, wd + u * 1024); }

#define BRD(r, s) (*(const bf16x8*)&xcur[(((r) * 2 + lh) * 66 + (s) + l31) * 8])
#define LOADROW(R, r)                                                           \
    { R[0] = BRD(r, 0);  R[1] = BRD(r, 1);  R[2] = BRD(r, 2);                   \
      R[3] = BRD(r, 32); R[4] = BRD(r, 33); R[5] = BRD(r, 34); }

#define TAPROW(i, RA, RB)                                                       \
    _Pragma("unroll")                                                           \
    for (int j = 0; j < 3; ++j) {                                               \
        const int tap = (i) * 3 + j;                                            \
        const short* wp = wcur + ((tap * 2 + lh) * 64 + l31) * 8;               \
        bf16x8 A0 = *(const bf16x8*)wp;                                         \
        bf16x8 A1 = *(const bf16x8*)(wp + 256);                                 \
        acc0[0] = __builtin_amdgcn_mfma_f32_32x32x16_bf16(A0, RA[j],     acc0[0], 0, 0, 0); \
        acc1[0] = __builtin_amdgcn_mfma_f32_32x32x16_bf16(A1, RA[j],     acc1[0], 0, 0, 0); \
        acc0[1] = __builtin_amdgcn_mfma_f32_32x32x16_bf16(A0, RA[3 + j], acc0[1], 0, 0, 0); \
        acc1[1] = __builtin_amdgcn_mfma_f32_32x32x16_bf16(A1, RA[3 + j], acc1[1], 0, 0, 0); \
        acc0[2] = __builtin_amdgcn_mfma_f32_32x32x16_bf16(A0, RB[j],     acc0[2], 0, 0, 0); \
        acc1[2] = __builtin_amdgcn_mfma_f32_32x32x16_bf16(A1, RB[j],     acc1[2], 0, 0, 0); \
        acc0[3] = __builtin_amdgcn_mfma_f32_32x32x16_bf16(A0, RB[3 + j], acc0[3], 0, 0, 0); \
        acc1[3] = __builtin_amdgcn_mfma_f32_32x32x16_bf16(A1, RB[3 + j], acc1[3], 0, 0, 0); \
    }

#define PHASE_EDGE()                                                            \
    __builtin_amdgcn_sched_barrier(0);                                          \
    __builtin_amdgcn_s_barrier();

    f32x16 acc0[4] = {}, acc1[4] = {};

    STAGE(0, 0);
    __syncthreads();

    for (int cc = 0; cc < 16; ++cc) {
        const int p = cc & 1;
        const short* xcur = lds + p * XBUF_SH;
        const short* wcur = lds + 2 * XBUF_SH + p * WTILE_SH;

        bf16x8 R0[6], R1[6];
        // ---- phase 0: load rows 0,1 + stage next chunk, then taprow 0
        LOADROW(R0, 2 * wid);
        LOADROW(R1, 2 * wid + 1);
        if (cc < 15) STAGE(cc + 1, p ^ 1);
        PHASE_EDGE();
        __builtin_amdgcn_s_setprio(1);
        TAPROW(0, R0, R1)
        __builtin_amdgcn_s_setprio(0);
        // ---- phase 1: load row 2, taprow 1
        LOADROW(R0, 2 * wid + 2);
        PHASE_EDGE();
        __builtin_amdgcn_s_setprio(1);
        TAPROW(1, R1, R0)
        __builtin_amdgcn_s_setprio(0);
        // ---- phase 2: load row 3, taprow 2
        LOADROW(R1, 2 * wid + 3);
        PHASE_EDGE();
        __builtin_amdgcn_s_setprio(1);
        TAPROW(2, R0, R1)
        __builtin_amdgcn_s_setprio(0);
        __syncthreads();               // buffer swap (vmcnt drain ~free: loads 1 chunk old)
    }
#undef STAGE
#undef BRD
#undef LOADROW
#undef TAPROW
#undef PHASE_EDGE

#pragma unroll
    for (int pf = 0; pf < 4; ++pf) {
        const int yb  = y0 + 2 * wid + (pf >> 1);
        const int xcb = 32 * (pf & 1) + l31;
#pragma unroll
        for (int r = 0; r < 16; ++r) {
            const int orow = (r & 3) + 8 * (r >> 2) + 4 * lh;
            const int o0   = oq * 64 + orow;
            __builtin_nontemporal_store(acc0[pf][r],
                &out[((size_t)(b * O_ + o0)      << 12) + yb * 64 + xcb]);
            __builtin_nontemporal_store(acc1[pf][r],
                &out[((size_t)(b * O_ + o0 + 32) << 12) + yb * 64 + xcb]);
        }
    }
}

// ---------------------------------------------------------------- launch ----
extern "C" void kernel_launch(void* const* d_in, const int* in_sizes, int n_in,
                              void* d_out, int out_size, void* d_ws, size_t ws_size,
                              hipStream_t stream) {
    const float* x    = (const float*)d_in[0];
    const float* W_fc = (const float*)d_in[1];
    const float* b_fc = (const float*)d_in[2];
    const float* bank = (const float*)d_in[3];
    float* out = (float*)d_out;

    short* xTb     = (short*)d_ws;
    short* worp    = (short*)((char*)d_ws + XT_BYTES);
    float* pooled4 = (float*)((char*)d_ws + XT_BYTES + WORP_BYTES);

    xprep_kernel<<<dim3(32, 16, 4), 256, 0, stream>>>(x, xTb, pooled4);
    mix_kernel<<<dim3(B_, 16), 256, 0, stream>>>(bank, pooled4, W_fc, b_fc, worp);
    conv_mfma<<<512, 256, 0, stream>>>(xTb, worp, out);
}